// Round 2
// baseline (193.209 us; speedup 1.0000x reference)
//
#include <hip/hip_runtime.h>
#include <cstddef>

#define BB 8
#define CC 512
#define LL 2048
#define TT 64

typedef short short8 __attribute__((ext_vector_type(8)));
typedef float floatx4 __attribute__((ext_vector_type(4)));
typedef unsigned short b16u;
typedef unsigned int u32;

static __device__ __forceinline__ unsigned f2bfu(float f) {
    unsigned u = __float_as_uint(f);
    u += 0x7fffu + ((u >> 16) & 1u);          // round-to-nearest-even
    return u >> 16;
}
static __device__ __forceinline__ float bfu2f(unsigned h) {
    return __uint_as_float(h << 16);
}

#define MFMA16(a, b, c) __builtin_amdgcn_mfma_f32_16x16x32_bf16((a), (b), (c), 0, 0, 0)

// ---------------------------------------------------------------------------
// K0: W1,W2 (64x512 fp32) -> bf16 hi/lo split, row-major.  (unchanged)
// ---------------------------------------------------------------------------
__global__ __launch_bounds__(256) void wcvt_kernel(
    const float* __restrict__ W1, const float* __restrict__ W2,
    b16u* __restrict__ W1h, b16u* __restrict__ W1l,
    b16u* __restrict__ W2h, b16u* __restrict__ W2l)
{
    int flat = blockIdx.x * 256 + threadIdx.x;        // 0..8191 float4 groups
    float4 v1 = *(const float4*)(W1 + (size_t)flat * 4);
    float4 v2 = *(const float4*)(W2 + (size_t)flat * 4);
    const float* e1 = (const float*)&v1;
    const float* e2 = (const float*)&v2;
    unsigned h1[4], l1[4], h2[4], l2[4];
#pragma unroll
    for (int k = 0; k < 4; ++k) {
        h1[k] = f2bfu(e1[k]); l1[k] = f2bfu(e1[k] - bfu2f(h1[k]));
        h2[k] = f2bfu(e2[k]); l2[k] = f2bfu(e2[k] - bfu2f(h2[k]));
    }
    uint2 a, b, c, d;
    a.x = h1[0] | (h1[1] << 16); a.y = h1[2] | (h1[3] << 16);
    b.x = l1[0] | (l1[1] << 16); b.y = l1[2] | (l1[3] << 16);
    c.x = h2[0] | (h2[1] << 16); c.y = h2[2] | (h2[3] << 16);
    d.x = l2[0] | (l2[1] << 16); d.y = l2[2] | (l2[3] << 16);
    *(uint2*)(W1h + (size_t)flat * 4) = a;
    *(uint2*)(W1l + (size_t)flat * 4) = b;
    *(uint2*)(W2h + (size_t)flat * 4) = c;
    *(uint2*)(W2l + (size_t)flat * 4) = d;
}

// ---------------------------------------------------------------------------
// K1: merged cvt+qk (unchanged): Q = W1@X, K = W2@X via split-bf16
// MFMA (hh+hl+lh) -> Qt/Kt (b, l, 64t) bf16.  grid (32 l-tiles, 8 b).
// ---------------------------------------------------------------------------
__global__ __launch_bounds__(256) void qkcvt_kernel(
    const float* __restrict__ x,
    const b16u* __restrict__ W1h, const b16u* __restrict__ W1l,
    const b16u* __restrict__ W2h, const b16u* __restrict__ W2l,
    b16u* __restrict__ Qt, b16u* __restrict__ Kt)
{
    __shared__ b16u Sxh[64 * 72];   // [l][c-chunk]
    __shared__ b16u Sxl[64 * 72];
    __shared__ b16u S1h[64 * 72];   // [t][c-chunk]
    __shared__ b16u S1l[64 * 72];
    __shared__ b16u S2h[64 * 72];
    __shared__ b16u S2l[64 * 72];
    const int b  = blockIdx.y;
    const int l0 = blockIdx.x * 64;
    const int tid = threadIdx.x;
    const int lane = tid & 63;
    const int w = tid >> 6;
    const int n16 = lane & 15;
    const int qd = lane >> 4;
    const float* xb = x + (size_t)b * CC * LL;

    const int cx = tid >> 2;
    const int sx = tid & 3;

    float4 xreg[4];
#pragma unroll
    for (int p = 0; p < 4; ++p)
        xreg[p] = *(const float4*)(xb + (size_t)cx * LL + l0 + (sx * 4 + p) * 4);

    floatx4 aq[4], ak[4];
#pragma unroll
    for (int nt = 0; nt < 4; ++nt) {
        aq[nt] = (floatx4){0.f, 0.f, 0.f, 0.f};
        ak[nt] = (floatx4){0.f, 0.f, 0.f, 0.f};
    }

    for (int c0 = 0; c0 < 512; c0 += 64) {
        __syncthreads();
#pragma unroll
        for (int p = 0; p < 4; ++p) {
            const float* e = (const float*)&xreg[p];
            int lbase = (sx * 4 + p) * 4;
#pragma unroll
            for (int k = 0; k < 4; ++k) {
                unsigned h = f2bfu(e[k]);
                unsigned lo = f2bfu(e[k] - bfu2f(h));
                Sxh[(lbase + k) * 72 + cx] = (b16u)h;
                Sxl[(lbase + k) * 72 + cx] = (b16u)lo;
            }
        }
#pragma unroll
        for (int p = 0; p < 2; ++p) {
            int flat = tid + p * 256;
            int t = flat >> 3, s8 = flat & 7;
            size_t off = (size_t)t * 512 + c0 + s8 * 8;
            *(uint4*)&S1h[t * 72 + s8 * 8] = *(const uint4*)(W1h + off);
            *(uint4*)&S1l[t * 72 + s8 * 8] = *(const uint4*)(W1l + off);
            *(uint4*)&S2h[t * 72 + s8 * 8] = *(const uint4*)(W2h + off);
            *(uint4*)&S2l[t * 72 + s8 * 8] = *(const uint4*)(W2l + off);
        }
        __syncthreads();
        if (c0 < 448) {
#pragma unroll
            for (int p = 0; p < 4; ++p)
                xreg[p] = *(const float4*)(xb + (size_t)(c0 + 64 + cx) * LL +
                                           l0 + (sx * 4 + p) * 4);
        }
#pragma unroll
        for (int kc = 0; kc < 2; ++kc) {
            const int ao = (w * 16 + n16) * 72 + kc * 32 + qd * 8;
            short8 a1h = *(const short8*)&S1h[ao];
            short8 a1l = *(const short8*)&S1l[ao];
            short8 a2h = *(const short8*)&S2h[ao];
            short8 a2l = *(const short8*)&S2l[ao];
#pragma unroll
            for (int nt = 0; nt < 4; ++nt) {
                const int bo = (nt * 16 + n16) * 72 + kc * 32 + qd * 8;
                short8 bh = *(const short8*)&Sxh[bo];
                short8 bl = *(const short8*)&Sxl[bo];
                aq[nt] = MFMA16(a1h, bh, aq[nt]);
                aq[nt] = MFMA16(a1h, bl, aq[nt]);
                aq[nt] = MFMA16(a1l, bh, aq[nt]);
                ak[nt] = MFMA16(a2h, bh, ak[nt]);
                ak[nt] = MFMA16(a2h, bl, ak[nt]);
                ak[nt] = MFMA16(a2l, bh, ak[nt]);
            }
        }
    }
#pragma unroll
    for (int nt = 0; nt < 4; ++nt) {
        int l = l0 + nt * 16 + n16;
        uint2 pq, pk;
        pq.x = f2bfu(aq[nt][0]) | (f2bfu(aq[nt][1]) << 16);
        pq.y = f2bfu(aq[nt][2]) | (f2bfu(aq[nt][3]) << 16);
        pk.x = f2bfu(ak[nt][0]) | (f2bfu(ak[nt][1]) << 16);
        pk.y = f2bfu(ak[nt][2]) | (f2bfu(ak[nt][3]) << 16);
        *(uint2*)(Qt + ((size_t)(b * 2048) + l) * 64 + w * 16 + qd * 4) = pq;
        *(uint2*)(Kt + ((size_t)(b * 2048) + l) * 64 + w * 16 + qd * 4) = pk;
    }
}

// ---------------------------------------------------------------------------
// K2: x -> XT bf16, TILE-MAJOR (b, t=32, c=512, 64i): each i-tile's V data
// is a contiguous 64 KB slab so fused V-frag reads are fully line-utilizing.
// ---------------------------------------------------------------------------
__global__ __launch_bounds__(256) void xcvt_kernel(
    const float* __restrict__ x, b16u* __restrict__ XT)
{
    int flat = blockIdx.x * 256 + threadIdx.x;   // 0..2097151 float4 groups
    int i4 = flat & 15;
    int t  = (flat >> 4) & 31;
    int c  = (flat >> 9) & 511;
    int b  = flat >> 18;
    float4 v = *(const float4*)(x + ((size_t)(b * 512 + c)) * 2048 + t * 64 + i4 * 4);
    uint2 wv;
    wv.x = f2bfu(v.x) | (f2bfu(v.y) << 16);
    wv.y = f2bfu(v.z) | (f2bfu(v.w) << 16);
    *(uint2*)(XT + (((size_t)(b * 32) + t) * 512 + c) * 64 + i4 * 4) = wv;
}

// ---------------------------------------------------------------------------
// K3: fused flash-style attention.  Block = (batch b, j-tile 128, c-half 256),
// grid 256 (1/CU, bid&7 = batch -> XCD L2 holds one 2 MB XT slab).
// 512 threads = 8 waves.  Loop 32 i-tiles:
//   - V(t+1) and K(t+2) prefetched global->REGISTERS (tile-major XT makes
//     these contiguous-slab reads; full L1/L2 line use, latency hidden by a
//     whole iteration of work)
//   - S-phase: wave (wi=w&3 i-quad, wh=w>>2 j-half) computes 16i x 64j of
//     S^T via MFMA(K,Q), exp(S-20), packs bf16 into XOR-swizzled LDS P tile
//   - PV-phase: wave (wq=w&3 c-quad, wh j-half) does 64c x 64j, V from regs,
//     P B-frags from LDS (swizzle -> conflict-free), 32 MFMAs, setprio(1)
//   - one barrier per tile (P double-buffered in LDS, V/K in regs)
// S is computed in both c-half blocks (20% MFMA overhead) to halve V traffic.
// ---------------------------------------------------------------------------
__global__ __launch_bounds__(512, 2) void fused_kernel(
    const float* __restrict__ x, const b16u* __restrict__ XT,
    const b16u* __restrict__ Qt, const b16u* __restrict__ Kt,
    const float* __restrict__ gamma, float* __restrict__ out)
{
    // loop: Ps [2][128][64] shorts (32 KB) + Zw (2 KB).  epilogue: st
    // 8 x 17408 B reuses [0,139264); Zf lives at 139264 (persistent).
    __shared__ __align__(16) char smem[139776];
    b16u*  Ps = (b16u*)smem;                    // 2 bufs of 8192 shorts
    float* Zw = (float*)(smem + 32768);         // [8][64]
    float* Zf = (float*)(smem + 139264);        // [128]

    const int bid = blockIdx.x;
    const int b   = bid & 7;
    const int c0  = ((bid >> 3) & 1) * 256;     // c-half
    const int j0  = (bid >> 4) * 128;           // j-tile
    const int tid = threadIdx.x;
    const int lane = tid & 63;
    const int w    = tid >> 6;
    const int n16  = lane & 15;
    const int qd   = lane >> 4;
    const int wi   = w & 3;        // S: i-quadrant (16 rows) / PV: c-quadrant
    const int wh   = w >> 2;       // j-half (64 cols) in both phases

    const b16u* Qb = Qt + ((size_t)(b * LL) + j0 + wh * 64 + n16) * 64 + qd * 8;
    const b16u* Kb = Kt + ((size_t)(b * LL) + wi * 16 + n16) * 64 + qd * 8;
    const b16u* Vb = XT + (size_t)b * (32 * 512 * 64) +
                     ((size_t)(c0 + wi * 64 + n16)) * 64 + qd * 8;

    // loop-invariant Q B-fragments (wave's 64 S j-cols)
    short8 qf[4][2];
#pragma unroll
    for (int nt2 = 0; nt2 < 4; ++nt2)
#pragma unroll
        for (int kc = 0; kc < 2; ++kc)
            qf[nt2][kc] = *(const short8*)(Qb + nt2 * (16 * 64) + kc * 32);

    floatx4 acc[4][4];
#pragma unroll
    for (int mt = 0; mt < 4; ++mt)
#pragma unroll
        for (int nt = 0; nt < 4; ++nt) acc[mt][nt] = (floatx4){0.f, 0.f, 0.f, 0.f};
    float zacc[4] = {0.f, 0.f, 0.f, 0.f};

#define KLOAD(KR, T)                                                       \
    {                                                                      \
        const b16u* kp = Kb + (size_t)(T) * (64 * 64);                     \
        KR[0] = *(const short8*)(kp);                                      \
        KR[1] = *(const short8*)(kp + 32);                                 \
    }

#define VLOAD(VR, T)                                                       \
    {                                                                      \
        const b16u* vp = Vb + (size_t)(T) * 32768;                         \
        _Pragma("unroll")                                                  \
        for (int mt = 0; mt < 4; ++mt) {                                   \
            VR[mt][0] = *(const short8*)(vp + mt * 1024);                  \
            VR[mt][1] = *(const short8*)(vp + mt * 1024 + 32);             \
        }                                                                  \
    }

    // S^T tile: D[m = i-local (wi quad), n = j]; lane holds 4 consecutive i
    // at fixed j -> 8B write into 16B-chunk XOR-swizzled row (key j&7 = n16&7)
#define SSTEP(PSOFF, KR)                                                   \
    {                                                                      \
        _Pragma("unroll")                                                  \
        for (int nt2 = 0; nt2 < 4; ++nt2) {                                \
            floatx4 sacc = (floatx4){0.f, 0.f, 0.f, 0.f};                  \
            sacc = MFMA16(KR[0], qf[nt2][0], sacc);                        \
            sacc = MFMA16(KR[1], qf[nt2][1], sacc);                        \
            float p0 = __expf(sacc[0] - 20.0f);                            \
            float p1 = __expf(sacc[1] - 20.0f);                            \
            float p2 = __expf(sacc[2] - 20.0f);                            \
            float p3 = __expf(sacc[3] - 20.0f);                            \
            zacc[nt2] += (p0 + p1) + (p2 + p3);                            \
            uint2 pk;                                                      \
            pk.x = f2bfu(p0) | (f2bfu(p1) << 16);                          \
            pk.y = f2bfu(p2) | (f2bfu(p3) << 16);                          \
            int jl = wh * 64 + nt2 * 16 + n16;                             \
            int phys = (wi * 2 + (qd >> 1)) ^ (n16 & 7);                   \
            *(uint2*)&Ps[(PSOFF) + jl * 64 + phys * 8 + (qd & 1) * 4] = pk;\
        }                                                                  \
    }

#define PVSTEP(PSOFF, VR)                                                  \
    {                                                                      \
        __builtin_amdgcn_s_setprio(1);                                     \
        _Pragma("unroll")                                                  \
        for (int kc = 0; kc < 2; ++kc) {                                   \
            short8 bfr[4];                                                 \
            _Pragma("unroll")                                              \
            for (int nt = 0; nt < 4; ++nt) {                               \
                int phys = (kc * 4 + qd) ^ (n16 & 7);                      \
                bfr[nt] = *(const short8*)&Ps[(PSOFF) +                    \
                    (wh * 64 + nt * 16 + n16) * 64 + phys * 8];            \
            }                                                              \
            _Pragma("unroll")                                              \
            for (int mt = 0; mt < 4; ++mt)                                 \
                _Pragma("unroll")                                          \
                for (int nt = 0; nt < 4; ++nt)                             \
                    acc[mt][nt] = MFMA16(VR[mt][kc], bfr[nt], acc[mt][nt]);\
        }                                                                  \
        __builtin_amdgcn_s_setprio(0);                                     \
    }

    short8 kA[2], kB[2], kT[2];
    short8 v0[4][2], v1[4][2];

    // prologue: S(0) -> Ps0, V(0) -> v0, K(1) -> kA
    KLOAD(kT, 0)
    VLOAD(v0, 0)
    SSTEP(0, kT)
    KLOAD(kA, 1)
    __syncthreads();

    for (int tt = 0; tt < 32; tt += 2) {
        // even iter t = tt: prefetch V(tt+1), K(tt+2); S(tt+1)->Ps1; PV(tt)
        VLOAD(v1, tt + 1)
        if (tt + 2 < 32) KLOAD(kB, tt + 2)
        SSTEP(8192, kA)
        PVSTEP(0, v0)
        __syncthreads();
        // odd iter t = tt+1: prefetch V(tt+2), K(tt+3); S(tt+2)->Ps0; PV(tt+1)
        if (tt + 2 < 32) {
            VLOAD(v0, tt + 2)
            if (tt + 3 < 32) KLOAD(kA, tt + 3)
            SSTEP(0, kB)
        }
        PVSTEP(8192, v1)
        __syncthreads();
    }
#undef KLOAD
#undef VLOAD
#undef SSTEP
#undef PVSTEP

    // ---- Z: reduce over qd (i within wave), then over the 4 wi waves ----
#pragma unroll
    for (int nt2 = 0; nt2 < 4; ++nt2) {
        float z = zacc[nt2];
        z += __shfl_xor(z, 16);
        z += __shfl_xor(z, 32);
        if (qd == 0) Zw[w * 64 + nt2 * 16 + n16] = z;
    }
    __syncthreads();
    if (tid < 128) {
        int hb = (tid >> 6) * 4;               // wave group with matching wh
        Zf[tid] = Zw[(hb + 0) * 64 + (tid & 63)] + Zw[(hb + 1) * 64 + (tid & 63)] +
                  Zw[(hb + 2) * 64 + (tid & 63)] + Zw[(hb + 3) * 64 + (tid & 63)];
    }
    __syncthreads();

    // ---- epilogue: scale by g/Z, per-wave LDS staging, coalesced store ----
    const float g = gamma[0];
    float* st = (float*)(smem + w * 17408);     // 64 x 68 floats per wave
#pragma unroll
    for (int nt = 0; nt < 4; ++nt) {
        float zi = g / Zf[wh * 64 + nt * 16 + n16];
#pragma unroll
        for (int mt = 0; mt < 4; ++mt)
#pragma unroll
            for (int r = 0; r < 4; ++r)
                st[(mt * 16 + qd * 4 + r) * 68 + nt * 16 + n16] = acc[mt][nt][r] * zi;
    }
    __syncthreads();
#pragma unroll
    for (int p = 0; p < 16; ++p) {
        int rl = qd * 16 + p;                   // c-local row in wave's quadrant
        int cg = c0 + wi * 64 + rl;
        size_t go = ((size_t)(b * CC) + cg) * 2048 + j0 + wh * 64 + n16 * 4;
        float4 v = *(const float4*)&st[rl * 68 + n16 * 4];
        float4 xv = *(const float4*)(x + go);
        v.x += xv.x; v.y += xv.y; v.z += xv.z; v.w += xv.w;
        *(float4*)(out + go) = v;
    }
}

// ---------------------------------------------------------------------------
extern "C" void kernel_launch(void* const* d_in, const int* in_sizes, int n_in,
                              void* d_out, int out_size, void* d_ws, size_t ws_size,
                              hipStream_t stream)
{
    (void)in_sizes; (void)n_in; (void)out_size; (void)ws_size;
    const float* x     = (const float*)d_in[0];
    const float* W1    = (const float*)d_in[1];
    const float* W2    = (const float*)d_in[2];
    const float* gamma = (const float*)d_in[3];
    float* out = (float*)d_out;

    b16u* Qt  = (b16u*)d_ws;                        // 2 MB
    b16u* Kt  = Qt  + (size_t)BB * LL * TT;         // 2 MB
    b16u* W1h = Kt  + (size_t)BB * LL * TT;         // 64 KB x4
    b16u* W1l = W1h + (size_t)TT * CC;
    b16u* W2h = W1l + (size_t)TT * CC;
    b16u* W2l = W2h + (size_t)TT * CC;
    b16u* XT  = W2l + (size_t)TT * CC;              // 16.8 MB, (b,t,c,64) bf16

    wcvt_kernel <<<dim3(32),      256, 0, stream>>>(W1, W2, W1h, W1l, W2h, W2l);
    xcvt_kernel <<<dim3(8192),    256, 0, stream>>>(x, XT);
    qkcvt_kernel<<<dim3(32, BB),  256, 0, stream>>>(x, W1h, W1l, W2h, W2l, Qt, Kt);
    fused_kernel<<<dim3(256),     512, 0, stream>>>(x, XT, Qt, Kt, gamma, out);
}